// Round 14
// baseline (916.051 us; speedup 1.0000x reference)
//
#include <hip/hip_runtime.h>

// ForexLSTM: 2-layer LSTM (B=1024, T=512, D=14, H=128) + batchnorm-over-batch + MLP(128->32->1)
//
// Round 24: R23 (DPP redistribution, best measured: 890us steady, despite 128-clamp
// + 118MB scratch) + accumulator-liveness shaping. Clamp pattern across 10 builds:
// allocator grants 256 VGPRs ONLY when pressure stays high through the whole body
// (R12's fat epilogue); every thin-epilogue build has a pressure valley (accumulators
// die at the gather) and gets clamped -- insensitive to attributes (x3) and to
// weight-side pins (R19: pinned the victims, valley remained). Untried shaping:
//   - pin C0/C1 (32 accumulator VGPRs) at the END of the phase body, after both
//     epilogues: reconstructs R12's pressure profile (acc live until last cellP) at
//     zero instruction cost. No new liveness at the MFMA-cluster peak (weights+acc
//     already co-live there); epilogue region rises to ~240 < 256 budget.
//   - Everything else R23-exact: DPP row-shift gather (row_shr:4/8/12 + selects,
//     pure full-rate VALU, no memory pipe), one cellP per lane (all 64 lanes useful),
//     fused-reciprocal cellP (5 exp2 + 2 rcp), wave-role merge, Whh1 kt0-1 regs /
//     kt2-3 LDS (82 KB), incremental x prefetch, launch_bounds(NT,1).

#define B_ 1024
#define T_ 512
#define D_ 14
#define H_ 128
#define NB 4
#define NT 512

#define L2E 1.44269504088896f
#define L2E2 2.88539008177793f

typedef _Float16 f16;
typedef _Float16 half4 __attribute__((ext_vector_type(4)));
typedef _Float16 half8 __attribute__((ext_vector_type(8)));
typedef float floatx4 __attribute__((ext_vector_type(4)));

__device__ __forceinline__ half8 ldfrag_s(const float* __restrict__ p, float s) {
    half8 r;
#pragma unroll
    for (int j = 0; j < 8; ++j) r[j] = (f16)(p[j] * s);
    return r;
}

// zero-instruction keep-alive (rule-17 technique): marks the value as used here,
// extending its live range without emitting code.
__device__ __forceinline__ void pinf(floatx4 v) { asm volatile("" :: "v"(v)); }

#define MFMA(a, b, c) __builtin_amdgcn_mfma_f32_16x16x32_f16((a), (b), (c), 0, 0, 0)

// Fused LSTM cell epilogue on pre-scaled gates:
//   pi,pf,po = y*log2e ; pg = 2x*log2e ; cs = 2*log2e*c (scaled cell state, updated).
// Returns h in true units. 5 exp2 + 2 rcp.
__device__ __forceinline__ float cellP(float pi, float pf, float pg, float po, float& cs)
{
    float a = __builtin_amdgcn_exp2f(-pi);
    float u = __builtin_amdgcn_exp2f(-pf);
    float b = __builtin_amdgcn_exp2f(pg);
    float d = __builtin_amdgcn_exp2f(-po);
    float t1 = 1.0f + a;
    float t3 = 1.0f + u;
    float t2 = __builtin_fmaf(t1, b, t1);          // (1+a)(1+b)
    float bm = b - 1.0f;
    float num = __builtin_fmaf(L2E2 * bm, t3, cs * t2);
    cs = num * __builtin_amdgcn_rcpf(t2 * t3);
    float e = __builtin_amdgcn_exp2f(cs);
    float t4 = 1.0f + d;
    float t5 = __builtin_fmaf(t4, e, t4);          // (1+d)(1+e)
    return (e - 1.0f) * __builtin_amdgcn_rcpf(t5);
}

// gather this lane's gate value from the MFMA accumulator via DPP row-shifts:
// dest lane l needs element rsel=(l>>2)&3 from source lane l-4*rsel (same DPP row).
__device__ __forceinline__ float dpp_gate(int rsel, floatx4 Cg)
{
    // row_shr:4 = 0x114, row_shr:8 = 0x118, row_shr:12 = 0x11C
    float s1 = __int_as_float(__builtin_amdgcn_update_dpp(
        0, __float_as_int(Cg[1]), 0x114, 0xF, 0xF, true));
    float s2 = __int_as_float(__builtin_amdgcn_update_dpp(
        0, __float_as_int(Cg[2]), 0x118, 0xF, 0xF, true));
    float s3 = __int_as_float(__builtin_amdgcn_update_dpp(
        0, __float_as_int(Cg[3]), 0x11C, 0xF, 0xF, true));
    return rsel == 0 ? Cg[0] : (rsel == 1 ? s1 : (rsel == 2 ? s2 : s3));
}

__global__ __launch_bounds__(NT, 1) void lstm_fused(
    const float* __restrict__ x,
    const float* __restrict__ Wih0, const float* __restrict__ Whh0,
    const float* __restrict__ bih0, const float* __restrict__ bhh0,
    const float* __restrict__ Wih1, const float* __restrict__ Whh1,
    const float* __restrict__ bih1, const float* __restrict__ bhh1,
    float* __restrict__ h2last)
{
    // LDS: 64 + 8 + 8 + 2 = 82 KB
    __shared__ __align__(16) f16 whh1lds[8][4][2][64][8];  // [wg][gate][kt-2][lane][e]
    __shared__ __align__(16) f16 h1f[2][4][64][8];         // [buf][kt][lane][e] B-frag
    __shared__ __align__(16) f16 h2f[2][4][64][8];
    __shared__ __align__(16) f16 xf[2][64][8];             // x_aug (K=16: 14 x, 0, 1.0)

    const int tid = threadIdx.x;
    const int lane = tid & 63;
    const int wv = tid >> 6;          // wave 0..7 == j-group for BOTH layers
    const int n = lane & 15;          // batch column (valid < NB) / A-row index
    const int q = lane >> 4;          // quad -> rows q*4+r
    const int b0 = blockIdx.x * NB;

    // ---- zero state buffers: h1f,h2f = 4096 dwords total; xf = 512 dwords ----
    {
        unsigned int* z1 = (unsigned int*)h1f;
        unsigned int* z2 = (unsigned int*)h2f;
#pragma unroll
        for (int i = 0; i < 4; ++i) {
            z1[tid + i * 512] = 0u;
            z2[tid + i * 512] = 0u;
        }
        ((unsigned int*)xf)[tid] = 0u;
    }
    __syncthreads();

    // ---- x_aug constants (k==15 -> 1.0 in BOTH buffers) + stage x(0) into xf[0] ----
    if (tid < NB) {
        xf[0][tid + 16][7] = (f16)1.0f;
        xf[1][tid + 16][7] = (f16)1.0f;
    }
    if (tid < 64) {
        int nn_ = tid & 15, kq = tid >> 4;
        if (nn_ < NB && kq < 2) {
            half8 v;
#pragma unroll
            for (int e = 0; e < 8; ++e) {
                int k = kq * 8 + e;
                v[e] = (k < D_) ? (f16)x[(size_t)(b0 + nn_) * T_ * D_ + k]
                                : (k == 15 ? (f16)1.0f : (f16)0.0f);
            }
            *(half8*)&xf[0][tid][0] = v;
        }
    }

    // incremental x-prefetch pointer (valid only for threads < NB*D_)
    const float* xpp = x + (size_t)(b0 + (tid & 3)) * T_ * D_ + D_ + (tid >> 2);

    // ---- per-wave weights: layer-0 j-group wv AND layer-1 j-group wv ----
    const int wg = wv;
    half8 aWhh0[4][4], aWih0[4];      // layer-0: all in regs
    half8 aWih1[4][4], aWhh1r[4][2];  // layer-1: Wih1 + Whh1 kt0-1 regs; kt2-3 LDS
#pragma unroll
    for (int g = 0; g < 4; ++g) {
        const float gs = (g == 2) ? L2E2 : L2E;   // g-gate rows pre-scaled 2x
        const int gr = g * 128 + wg * 16 + n;
#pragma unroll
        for (int kt = 0; kt < 4; ++kt)
            aWhh0[g][kt] = ldfrag_s(Whh0 + (size_t)gr * H_ + kt * 32 + q * 8, gs);
        half8 w0;
#pragma unroll
        for (int e = 0; e < 8; ++e) {
            int k = q * 8 + e;
            if (k < D_)       w0[e] = (f16)(Wih0[(size_t)gr * D_ + k] * gs);
            else if (k == 15) w0[e] = (f16)((bih0[gr] + bhh0[gr]) * gs);
            else              w0[e] = (f16)0.0f;
        }
        aWih0[g] = w0;
#pragma unroll
        for (int kt = 0; kt < 4; ++kt) {
            aWih1[g][kt] = ldfrag_s(Wih1 + (size_t)gr * H_ + kt * 32 + q * 8, gs);
            half8 wf = ldfrag_s(Whh1 + (size_t)gr * H_ + kt * 32 + q * 8, gs);
            if (kt < 2) aWhh1r[g][kt] = wf;
            else        *(half8*)&whh1lds[wg][g][kt - 2][lane][0] = wf;
        }
    }

    // ---- per-lane (dest-cell) constants for the DPP-redistributed epilogue ----
    const int colp = lane & 3;        // dest batch column (0..3, all valid)
    const int rsel = (lane >> 2) & 3; // source accumulator element / row-within-quad
    const int jj2 = q * 4 + rsel;     // dest cell row j within the wave's 16-row group
    const int ktD = wg >> 1;
    const int rowD = colp + 16 * ((wg & 1) * 2 + (q >> 1));
    const int eD = (q & 1) * 4 + rsel;
    float bias1v[4];
#pragma unroll
    for (int g = 0; g < 4; ++g) {
        const float gs = (g == 2) ? L2E2 : L2E;
        const int gb = g * 128 + wg * 16 + jj2;
        bias1v[g] = (bih1[gb] + bhh1[gb]) * gs;
    }

    float cs1 = 0.0f;   // layer-0 cell state for cell (jj2, colp), pre-scaled 2*log2e
    float cs2 = 0.0f;   // layer-1 cell state
    __syncthreads();

    // phase p: layer-0 computes h1(p) [p<T], layer-1 computes h2(p-1) [p>=1]
    for (int p = 0; p <= T_; ++p) {
        const int cur = p & 1, nxt = cur ^ 1;
        const bool doA = (p < T_);
        const bool doB = (p >= 1);

        float xp = 0.0f;
        if (tid < NB * D_ && (p + 1) < T_) xp = *xpp;

        floatx4 C0[4], C1[4];
#pragma unroll
        for (int g = 0; g < 4; ++g) {
            C0[g] = floatx4{0.f, 0.f, 0.f, 0.f};
            C1[g] = floatx4{0.f, 0.f, 0.f, 0.f};
        }

        if (doA) {
            half8 bx = *(const half8*)&xf[cur][lane][0];
#pragma unroll
            for (int g = 0; g < 4; ++g) C0[g] = MFMA(aWih0[g], bx, C0[g]);
        }
        // shared h1f fragments: feed layer-0 recurrence AND layer-1 input
#pragma unroll
        for (int kt = 0; kt < 4; ++kt) {
            half8 bh = *(const half8*)&h1f[cur][kt][lane][0];
            if (doA) {
#pragma unroll
                for (int g = 0; g < 4; ++g) C0[g] = MFMA(aWhh0[g][kt], bh, C0[g]);
            }
            if (doB) {
#pragma unroll
                for (int g = 0; g < 4; ++g) C1[g] = MFMA(aWih1[g][kt], bh, C1[g]);
            }
        }
        if (doB) {
#pragma unroll
            for (int kt = 0; kt < 2; ++kt) {
                half8 bh = *(const half8*)&h2f[cur][kt][lane][0];
#pragma unroll
                for (int g = 0; g < 4; ++g) C1[g] = MFMA(aWhh1r[g][kt], bh, C1[g]);
            }
#pragma unroll
            for (int kt = 2; kt < 4; ++kt) {
                half8 bh = *(const half8*)&h2f[cur][kt][lane][0];
#pragma unroll
                for (int g = 0; g < 4; ++g) {
                    half8 aw = *(const half8*)&whh1lds[wg][g][kt - 2][lane][0];
                    C1[g] = MFMA(aw, bh, C1[g]);
                }
            }
        }

        // ---- layer-0 epilogue: DPP-gather 4 gates, one cellP per lane ----
        if (doA) {
            float g0 = dpp_gate(rsel, C0[0]);
            float g1 = dpp_gate(rsel, C0[1]);
            float g2 = dpp_gate(rsel, C0[2]);
            float g3 = dpp_gate(rsel, C0[3]);
            float h0 = cellP(g0, g1, g2, g3, cs1);
            h1f[nxt][ktD][rowD][eD] = (f16)h0;
        }

        // ---- layer-1 epilogue ----
        if (doB) {
            float g0 = dpp_gate(rsel, C1[0]) + bias1v[0];
            float g1 = dpp_gate(rsel, C1[1]) + bias1v[1];
            float g2 = dpp_gate(rsel, C1[2]) + bias1v[2];
            float g3 = dpp_gate(rsel, C1[3]) + bias1v[3];
            float hv = cellP(g0, g1, g2, g3, cs2);
            h2f[nxt][ktD][rowD][eD] = (f16)hv;
            if (p == T_)
                h2last[(size_t)(b0 + colp) * H_ + wg * 16 + jj2] = hv;
        }

        // ---- accumulator-liveness shaping: keep C0/C1 live until after both
        // epilogues (zero instructions). Reconstructs R12's high-pressure profile --
        // the only shape the allocator has ever granted 256 VGPRs / no scratch.
#pragma unroll
        for (int g = 0; g < 4; ++g) { pinf(C0[g]); pinf(C1[g]); }

        if (tid < NB * D_ && (p + 1) < T_) {
            int k = tid >> 2;
            xf[nxt][(tid & 3) + 16 * (k >> 3)][k & 7] = (f16)xp;
            xpp += D_;
        }
        __syncthreads();
    }
}

// batch-norm statistics over the batch dim: 1 block, 1024 threads
__global__ void bn_stats(const float* __restrict__ h2last, float* __restrict__ stats)
{
    __shared__ float red[2][8][128];
    const int tid = threadIdx.x;
    const int j = tid & 127, bs = tid >> 7;
    float s = 0.0f, ss = 0.0f;
    for (int bb = 0; bb < 128; ++bb) {
        float v = h2last[(size_t)(bb * 8 + bs) * H_ + j];
        s += v;
        ss += v * v;
    }
    red[0][bs][j] = s;
    red[1][bs][j] = ss;
    __syncthreads();
    if (tid < 128) {
        float S = 0.0f, SS = 0.0f;
#pragma unroll
        for (int k = 0; k < 8; ++k) { S += red[0][k][tid]; SS += red[1][k][tid]; }
        float mu = S * (1.0f / 1024.0f);
        float var = SS * (1.0f / 1024.0f) - mu * mu;
        stats[tid] = mu;
        stats[128 + tid] = __builtin_amdgcn_rsqf(var + 1e-5f);
    }
}

// normalize + MLP head: 8 blocks x 128 threads, one batch element per thread
__global__ void bn_mlp(const float* __restrict__ h2last, const float* __restrict__ stats,
                       const float* __restrict__ gamma, const float* __restrict__ beta,
                       const float* __restrict__ W1, const float* __restrict__ b1,
                       const float* __restrict__ W2, const float* __restrict__ b2,
                       float* __restrict__ out)
{
    __shared__ float W1T[128][33];
    __shared__ float mus[128], isds[128], gs[128], bts[128], w2s[32];
    const int tid = threadIdx.x;
    const int b = blockIdx.x * 128 + tid;

    for (int i = tid; i < 4096; i += 128) {
        int k = i >> 7, j = i & 127;
        W1T[j][k] = W1[i];
    }
    mus[tid] = stats[tid];
    isds[tid] = stats[128 + tid];
    gs[tid] = gamma[tid];
    bts[tid] = beta[tid];
    if (tid < 32) w2s[tid] = W2[tid];
    __syncthreads();

    float z[32];
#pragma unroll
    for (int k = 0; k < 32; ++k) z[k] = b1[k];

    for (int j = 0; j < 128; ++j) {
        float nv = (h2last[(size_t)b * H_ + j] - mus[j]) * isds[j] * gs[j] + bts[j];
#pragma unroll
        for (int k = 0; k < 32; ++k) z[k] += W1T[j][k] * nv;
    }
    float o = b2[0];
#pragma unroll
    for (int k = 0; k < 32; ++k) o += w2s[k] * fmaxf(z[k], 0.0f);
    out[b] = o;
}

extern "C" void kernel_launch(void* const* d_in, const int* in_sizes, int n_in,
                              void* d_out, int out_size, void* d_ws, size_t ws_size,
                              hipStream_t stream)
{
    const float* x    = (const float*)d_in[0];
    const float* Wih0 = (const float*)d_in[1];
    const float* Whh0 = (const float*)d_in[2];
    const float* bih0 = (const float*)d_in[3];
    const float* bhh0 = (const float*)d_in[4];
    const float* Wih1 = (const float*)d_in[5];
    const float* Whh1 = (const float*)d_in[6];
    const float* bih1 = (const float*)d_in[7];
    const float* bhh1 = (const float*)d_in[8];
    const float* gamma = (const float*)d_in[9];
    const float* beta  = (const float*)d_in[10];
    const float* W1 = (const float*)d_in[11];
    const float* b1 = (const float*)d_in[12];
    const float* W2 = (const float*)d_in[13];
    const float* b2 = (const float*)d_in[14];

    float* h2last = (float*)d_ws;              // 1024*128 floats = 512 KB
    float* stats  = h2last + (size_t)B_ * H_;  // 256 floats
    float* out = (float*)d_out;

    hipLaunchKernelGGL(lstm_fused, dim3(B_ / NB), dim3(NT), 0, stream,
                       x, Wih0, Whh0, bih0, bhh0, Wih1, Whh1, bih1, bhh1, h2last);
    hipLaunchKernelGGL(bn_stats, dim3(1), dim3(1024), 0, stream, h2last, stats);
    hipLaunchKernelGGL(bn_mlp, dim3(8), dim3(128), 0, stream,
                       h2last, stats, gamma, beta, W1, b1, W2, b2, out);
}

// Round 15
// 913.011 us; speedup vs baseline: 1.0033x; 1.0033x over previous
//
#include <hip/hip_runtime.h>

// ForexLSTM: 2-layer LSTM (B=1024, T=512, D=14, H=128) + batchnorm-over-batch + MLP(128->32->1)
//
// Round 25: revert R24's accumulator pins -> R23 exact (best measured: 890us steady,
// 912.6 reported). R24 falsified the pressure-valley model: pinning C0/C1 through the
// epilogue left VGPR=128 / WRITE=67MB unchanged and cost ~2% (scheduling constraint,
// no allocator effect). Five mechanisms (3 attributes, weight pins, acc pins) all
// failed to lift the 128-VGPR clamp -> it is a pre-RA structural decision; accepted.
// R23 wins DESPITE the clamp because the DPP epilogue is the only redistribution
// transport with no memory pipe: MfmaUtil 40.7->43.4 vs R12, dur 964.7->890.
//
// Kernel structure (final):
//   - Wave-role merge: each of 8 waves computes j-group wg=wave for BOTH layers;
//     h1f fragments read once feed layer-0 recurrence AND layer-1 input MFMAs.
//   - DPP redistribution: dest lane l (cell j=q*4+rsel, col=l&3; rsel=(l>>2)&3)
//     gathers C[g][rsel] from lane l-4*rsel via v_mov_dpp row_shr:4/8/12 + selects --
//     pure full-rate VALU, no LDS crossbar (bank conflicts 0). One cellP per lane
//     (all 64 lanes useful; R12 wasted 48/64). Per-lane trans 56->14 per phase.
//   - Fused-reciprocal cellP on log2e-prefolded weights: 5 exp2 + 2 rcp per cell.
//   - Whh1 kt0-1 in regs, kt2-3 in LDS (82 KB total); incremental x prefetch;
//     __launch_bounds__(NT, 1); 513 barrier-synced phases (L0(t=p) + L1(t=p-1)).

#define B_ 1024
#define T_ 512
#define D_ 14
#define H_ 128
#define NB 4
#define NT 512

#define L2E 1.44269504088896f
#define L2E2 2.88539008177793f

typedef _Float16 f16;
typedef _Float16 half4 __attribute__((ext_vector_type(4)));
typedef _Float16 half8 __attribute__((ext_vector_type(8)));
typedef float floatx4 __attribute__((ext_vector_type(4)));

__device__ __forceinline__ half8 ldfrag_s(const float* __restrict__ p, float s) {
    half8 r;
#pragma unroll
    for (int j = 0; j < 8; ++j) r[j] = (f16)(p[j] * s);
    return r;
}

#define MFMA(a, b, c) __builtin_amdgcn_mfma_f32_16x16x32_f16((a), (b), (c), 0, 0, 0)

// Fused LSTM cell epilogue on pre-scaled gates:
//   pi,pf,po = y*log2e ; pg = 2x*log2e ; cs = 2*log2e*c (scaled cell state, updated).
// Returns h in true units. 5 exp2 + 2 rcp.
__device__ __forceinline__ float cellP(float pi, float pf, float pg, float po, float& cs)
{
    float a = __builtin_amdgcn_exp2f(-pi);
    float u = __builtin_amdgcn_exp2f(-pf);
    float b = __builtin_amdgcn_exp2f(pg);
    float d = __builtin_amdgcn_exp2f(-po);
    float t1 = 1.0f + a;
    float t3 = 1.0f + u;
    float t2 = __builtin_fmaf(t1, b, t1);          // (1+a)(1+b)
    float bm = b - 1.0f;
    float num = __builtin_fmaf(L2E2 * bm, t3, cs * t2);
    cs = num * __builtin_amdgcn_rcpf(t2 * t3);
    float e = __builtin_amdgcn_exp2f(cs);
    float t4 = 1.0f + d;
    float t5 = __builtin_fmaf(t4, e, t4);          // (1+d)(1+e)
    return (e - 1.0f) * __builtin_amdgcn_rcpf(t5);
}

// gather this lane's gate value from the MFMA accumulator via DPP row-shifts:
// dest lane l needs element rsel=(l>>2)&3 from source lane l-4*rsel (same DPP row).
__device__ __forceinline__ float dpp_gate(int rsel, floatx4 Cg)
{
    // row_shr:4 = 0x114, row_shr:8 = 0x118, row_shr:12 = 0x11C
    float s1 = __int_as_float(__builtin_amdgcn_update_dpp(
        0, __float_as_int(Cg[1]), 0x114, 0xF, 0xF, true));
    float s2 = __int_as_float(__builtin_amdgcn_update_dpp(
        0, __float_as_int(Cg[2]), 0x118, 0xF, 0xF, true));
    float s3 = __int_as_float(__builtin_amdgcn_update_dpp(
        0, __float_as_int(Cg[3]), 0x11C, 0xF, 0xF, true));
    return rsel == 0 ? Cg[0] : (rsel == 1 ? s1 : (rsel == 2 ? s2 : s3));
}

__global__ __launch_bounds__(NT, 1) void lstm_fused(
    const float* __restrict__ x,
    const float* __restrict__ Wih0, const float* __restrict__ Whh0,
    const float* __restrict__ bih0, const float* __restrict__ bhh0,
    const float* __restrict__ Wih1, const float* __restrict__ Whh1,
    const float* __restrict__ bih1, const float* __restrict__ bhh1,
    float* __restrict__ h2last)
{
    // LDS: 64 + 8 + 8 + 2 = 82 KB
    __shared__ __align__(16) f16 whh1lds[8][4][2][64][8];  // [wg][gate][kt-2][lane][e]
    __shared__ __align__(16) f16 h1f[2][4][64][8];         // [buf][kt][lane][e] B-frag
    __shared__ __align__(16) f16 h2f[2][4][64][8];
    __shared__ __align__(16) f16 xf[2][64][8];             // x_aug (K=16: 14 x, 0, 1.0)

    const int tid = threadIdx.x;
    const int lane = tid & 63;
    const int wv = tid >> 6;          // wave 0..7 == j-group for BOTH layers
    const int n = lane & 15;          // batch column (valid < NB) / A-row index
    const int q = lane >> 4;          // quad -> rows q*4+r
    const int b0 = blockIdx.x * NB;

    // ---- zero state buffers: h1f,h2f = 4096 dwords total; xf = 512 dwords ----
    {
        unsigned int* z1 = (unsigned int*)h1f;
        unsigned int* z2 = (unsigned int*)h2f;
#pragma unroll
        for (int i = 0; i < 4; ++i) {
            z1[tid + i * 512] = 0u;
            z2[tid + i * 512] = 0u;
        }
        ((unsigned int*)xf)[tid] = 0u;
    }
    __syncthreads();

    // ---- x_aug constants (k==15 -> 1.0 in BOTH buffers) + stage x(0) into xf[0] ----
    if (tid < NB) {
        xf[0][tid + 16][7] = (f16)1.0f;
        xf[1][tid + 16][7] = (f16)1.0f;
    }
    if (tid < 64) {
        int nn_ = tid & 15, kq = tid >> 4;
        if (nn_ < NB && kq < 2) {
            half8 v;
#pragma unroll
            for (int e = 0; e < 8; ++e) {
                int k = kq * 8 + e;
                v[e] = (k < D_) ? (f16)x[(size_t)(b0 + nn_) * T_ * D_ + k]
                                : (k == 15 ? (f16)1.0f : (f16)0.0f);
            }
            *(half8*)&xf[0][tid][0] = v;
        }
    }

    // incremental x-prefetch pointer (valid only for threads < NB*D_)
    const float* xpp = x + (size_t)(b0 + (tid & 3)) * T_ * D_ + D_ + (tid >> 2);

    // ---- per-wave weights: layer-0 j-group wv AND layer-1 j-group wv ----
    const int wg = wv;
    half8 aWhh0[4][4], aWih0[4];      // layer-0: all in regs
    half8 aWih1[4][4], aWhh1r[4][2];  // layer-1: Wih1 + Whh1 kt0-1 regs; kt2-3 LDS
#pragma unroll
    for (int g = 0; g < 4; ++g) {
        const float gs = (g == 2) ? L2E2 : L2E;   // g-gate rows pre-scaled 2x
        const int gr = g * 128 + wg * 16 + n;
#pragma unroll
        for (int kt = 0; kt < 4; ++kt)
            aWhh0[g][kt] = ldfrag_s(Whh0 + (size_t)gr * H_ + kt * 32 + q * 8, gs);
        half8 w0;
#pragma unroll
        for (int e = 0; e < 8; ++e) {
            int k = q * 8 + e;
            if (k < D_)       w0[e] = (f16)(Wih0[(size_t)gr * D_ + k] * gs);
            else if (k == 15) w0[e] = (f16)((bih0[gr] + bhh0[gr]) * gs);
            else              w0[e] = (f16)0.0f;
        }
        aWih0[g] = w0;
#pragma unroll
        for (int kt = 0; kt < 4; ++kt) {
            aWih1[g][kt] = ldfrag_s(Wih1 + (size_t)gr * H_ + kt * 32 + q * 8, gs);
            half8 wf = ldfrag_s(Whh1 + (size_t)gr * H_ + kt * 32 + q * 8, gs);
            if (kt < 2) aWhh1r[g][kt] = wf;
            else        *(half8*)&whh1lds[wg][g][kt - 2][lane][0] = wf;
        }
    }

    // ---- per-lane (dest-cell) constants for the DPP-redistributed epilogue ----
    const int colp = lane & 3;        // dest batch column (0..3, all valid)
    const int rsel = (lane >> 2) & 3; // source accumulator element / row-within-quad
    const int jj2 = q * 4 + rsel;     // dest cell row j within the wave's 16-row group
    const int ktD = wg >> 1;
    const int rowD = colp + 16 * ((wg & 1) * 2 + (q >> 1));
    const int eD = (q & 1) * 4 + rsel;
    float bias1v[4];
#pragma unroll
    for (int g = 0; g < 4; ++g) {
        const float gs = (g == 2) ? L2E2 : L2E;
        const int gb = g * 128 + wg * 16 + jj2;
        bias1v[g] = (bih1[gb] + bhh1[gb]) * gs;
    }

    float cs1 = 0.0f;   // layer-0 cell state for cell (jj2, colp), pre-scaled 2*log2e
    float cs2 = 0.0f;   // layer-1 cell state
    __syncthreads();

    // phase p: layer-0 computes h1(p) [p<T], layer-1 computes h2(p-1) [p>=1]
    for (int p = 0; p <= T_; ++p) {
        const int cur = p & 1, nxt = cur ^ 1;
        const bool doA = (p < T_);
        const bool doB = (p >= 1);

        float xp = 0.0f;
        if (tid < NB * D_ && (p + 1) < T_) xp = *xpp;

        floatx4 C0[4], C1[4];
#pragma unroll
        for (int g = 0; g < 4; ++g) {
            C0[g] = floatx4{0.f, 0.f, 0.f, 0.f};
            C1[g] = floatx4{0.f, 0.f, 0.f, 0.f};
        }

        if (doA) {
            half8 bx = *(const half8*)&xf[cur][lane][0];
#pragma unroll
            for (int g = 0; g < 4; ++g) C0[g] = MFMA(aWih0[g], bx, C0[g]);
        }
        // shared h1f fragments: feed layer-0 recurrence AND layer-1 input
#pragma unroll
        for (int kt = 0; kt < 4; ++kt) {
            half8 bh = *(const half8*)&h1f[cur][kt][lane][0];
            if (doA) {
#pragma unroll
                for (int g = 0; g < 4; ++g) C0[g] = MFMA(aWhh0[g][kt], bh, C0[g]);
            }
            if (doB) {
#pragma unroll
                for (int g = 0; g < 4; ++g) C1[g] = MFMA(aWih1[g][kt], bh, C1[g]);
            }
        }
        if (doB) {
#pragma unroll
            for (int kt = 0; kt < 2; ++kt) {
                half8 bh = *(const half8*)&h2f[cur][kt][lane][0];
#pragma unroll
                for (int g = 0; g < 4; ++g) C1[g] = MFMA(aWhh1r[g][kt], bh, C1[g]);
            }
#pragma unroll
            for (int kt = 2; kt < 4; ++kt) {
                half8 bh = *(const half8*)&h2f[cur][kt][lane][0];
#pragma unroll
                for (int g = 0; g < 4; ++g) {
                    half8 aw = *(const half8*)&whh1lds[wg][g][kt - 2][lane][0];
                    C1[g] = MFMA(aw, bh, C1[g]);
                }
            }
        }

        // ---- layer-0 epilogue: DPP-gather 4 gates, one cellP per lane ----
        if (doA) {
            float g0 = dpp_gate(rsel, C0[0]);
            float g1 = dpp_gate(rsel, C0[1]);
            float g2 = dpp_gate(rsel, C0[2]);
            float g3 = dpp_gate(rsel, C0[3]);
            float h0 = cellP(g0, g1, g2, g3, cs1);
            h1f[nxt][ktD][rowD][eD] = (f16)h0;
        }

        // ---- layer-1 epilogue ----
        if (doB) {
            float g0 = dpp_gate(rsel, C1[0]) + bias1v[0];
            float g1 = dpp_gate(rsel, C1[1]) + bias1v[1];
            float g2 = dpp_gate(rsel, C1[2]) + bias1v[2];
            float g3 = dpp_gate(rsel, C1[3]) + bias1v[3];
            float hv = cellP(g0, g1, g2, g3, cs2);
            h2f[nxt][ktD][rowD][eD] = (f16)hv;
            if (p == T_)
                h2last[(size_t)(b0 + colp) * H_ + wg * 16 + jj2] = hv;
        }

        if (tid < NB * D_ && (p + 1) < T_) {
            int k = tid >> 2;
            xf[nxt][(tid & 3) + 16 * (k >> 3)][k & 7] = (f16)xp;
            xpp += D_;
        }
        __syncthreads();
    }
}

// batch-norm statistics over the batch dim: 1 block, 1024 threads
__global__ void bn_stats(const float* __restrict__ h2last, float* __restrict__ stats)
{
    __shared__ float red[2][8][128];
    const int tid = threadIdx.x;
    const int j = tid & 127, bs = tid >> 7;
    float s = 0.0f, ss = 0.0f;
    for (int bb = 0; bb < 128; ++bb) {
        float v = h2last[(size_t)(bb * 8 + bs) * H_ + j];
        s += v;
        ss += v * v;
    }
    red[0][bs][j] = s;
    red[1][bs][j] = ss;
    __syncthreads();
    if (tid < 128) {
        float S = 0.0f, SS = 0.0f;
#pragma unroll
        for (int k = 0; k < 8; ++k) { S += red[0][k][tid]; SS += red[1][k][tid]; }
        float mu = S * (1.0f / 1024.0f);
        float var = SS * (1.0f / 1024.0f) - mu * mu;
        stats[tid] = mu;
        stats[128 + tid] = __builtin_amdgcn_rsqf(var + 1e-5f);
    }
}

// normalize + MLP head: 8 blocks x 128 threads, one batch element per thread
__global__ void bn_mlp(const float* __restrict__ h2last, const float* __restrict__ stats,
                       const float* __restrict__ gamma, const float* __restrict__ beta,
                       const float* __restrict__ W1, const float* __restrict__ b1,
                       const float* __restrict__ W2, const float* __restrict__ b2,
                       float* __restrict__ out)
{
    __shared__ float W1T[128][33];
    __shared__ float mus[128], isds[128], gs[128], bts[128], w2s[32];
    const int tid = threadIdx.x;
    const int b = blockIdx.x * 128 + tid;

    for (int i = tid; i < 4096; i += 128) {
        int k = i >> 7, j = i & 127;
        W1T[j][k] = W1[i];
    }
    mus[tid] = stats[tid];
    isds[tid] = stats[128 + tid];
    gs[tid] = gamma[tid];
    bts[tid] = beta[tid];
    if (tid < 32) w2s[tid] = W2[tid];
    __syncthreads();

    float z[32];
#pragma unroll
    for (int k = 0; k < 32; ++k) z[k] = b1[k];

    for (int j = 0; j < 128; ++j) {
        float nv = (h2last[(size_t)b * H_ + j] - mus[j]) * isds[j] * gs[j] + bts[j];
#pragma unroll
        for (int k = 0; k < 32; ++k) z[k] += W1T[j][k] * nv;
    }
    float o = b2[0];
#pragma unroll
    for (int k = 0; k < 32; ++k) o += w2s[k] * fmaxf(z[k], 0.0f);
    out[b] = o;
}

extern "C" void kernel_launch(void* const* d_in, const int* in_sizes, int n_in,
                              void* d_out, int out_size, void* d_ws, size_t ws_size,
                              hipStream_t stream)
{
    const float* x    = (const float*)d_in[0];
    const float* Wih0 = (const float*)d_in[1];
    const float* Whh0 = (const float*)d_in[2];
    const float* bih0 = (const float*)d_in[3];
    const float* bhh0 = (const float*)d_in[4];
    const float* Wih1 = (const float*)d_in[5];
    const float* Whh1 = (const float*)d_in[6];
    const float* bih1 = (const float*)d_in[7];
    const float* bhh1 = (const float*)d_in[8];
    const float* gamma = (const float*)d_in[9];
    const float* beta  = (const float*)d_in[10];
    const float* W1 = (const float*)d_in[11];
    const float* b1 = (const float*)d_in[12];
    const float* W2 = (const float*)d_in[13];
    const float* b2 = (const float*)d_in[14];

    float* h2last = (float*)d_ws;              // 1024*128 floats = 512 KB
    float* stats  = h2last + (size_t)B_ * H_;  // 256 floats
    float* out = (float*)d_out;

    hipLaunchKernelGGL(lstm_fused, dim3(B_ / NB), dim3(NT), 0, stream,
                       x, Wih0, Whh0, bih0, bhh0, Wih1, Whh1, bih1, bhh1, h2last);
    hipLaunchKernelGGL(bn_stats, dim3(1), dim3(1024), 0, stream, h2last, stats);
    hipLaunchKernelGGL(bn_mlp, dim3(8), dim3(128), 0, stream,
                       h2last, stats, gamma, beta, W1, b1, W2, b2, out);
}

// Round 16
// 898.945 us; speedup vs baseline: 1.0190x; 1.0156x over previous
//
#include <hip/hip_runtime.h>

// ForexLSTM: 2-layer LSTM (B=1024, T=512, D=14, H=128) + batchnorm-over-batch + MLP(128->32->1)
//
// Round 26: anti-phase retry on the R23/R25 base (891us steady, reproduced twice).
// Pipe accounting says MFMA (~2017 cyc/SIMD/phase) and VALU (~1530) are ADDITIVE =
// 85% of the 4170-cyc phase: both waves/SIMD are lockstep (MFMA cluster together,
// epilogue together). Anti-phasing the two waves' segment order has a ~450us floor.
// R13 (first attempt) replay-diverged -- but its memory pattern (reads [cur], writes
// [nxt], disjoint per-wave slots, 1 barrier/phase) is identical to the proven-safe
// R12; the only suspect delta was lambdas + sched_barrier(0) in wave-divergent code
// (rule-18/19 miscompile class). This retry removes every suspect construct:
//   - plain if/else on grpY = (0x96>>wv)&1 (waves {1,2,4,7} run L1;L0 -- anti-phases
//     both contiguous and round-robin wave->SIMD pairings), segments as macros:
//     no lambdas, no sched_barrier, no setprio, no inline asm.
//   - cost: h1f fragments read in both segments (+4 ds_read/wave/phase, LDS pipe
//     ~2000 cyc/CU, still under the MFMA floor). C0/C1 now segment-local.
//   - Everything else R23/R25-exact: DPP row-shift gather epilogue (no memory pipe,
//     bank conflicts 0), one cellP per lane, fused-reciprocal cellP (5 exp2 + 2 rcp),
//     wave-role merge, Whh1 kt0-1 regs / kt2-3 LDS (82 KB), incremental x prefetch,
//     __launch_bounds__(NT, 1), 513 barrier-synced phases.
// Decision rule: replay-divergence again => anti-phase is intrinsically unsafe here,
// permanent abandon, revert to R25. Neutral => R25 stands as final.

#define B_ 1024
#define T_ 512
#define D_ 14
#define H_ 128
#define NB 4
#define NT 512

#define L2E 1.44269504088896f
#define L2E2 2.88539008177793f

typedef _Float16 f16;
typedef _Float16 half4 __attribute__((ext_vector_type(4)));
typedef _Float16 half8 __attribute__((ext_vector_type(8)));
typedef float floatx4 __attribute__((ext_vector_type(4)));

__device__ __forceinline__ half8 ldfrag_s(const float* __restrict__ p, float s) {
    half8 r;
#pragma unroll
    for (int j = 0; j < 8; ++j) r[j] = (f16)(p[j] * s);
    return r;
}

#define MFMA(a, b, c) __builtin_amdgcn_mfma_f32_16x16x32_f16((a), (b), (c), 0, 0, 0)

// Fused LSTM cell epilogue on pre-scaled gates:
//   pi,pf,po = y*log2e ; pg = 2x*log2e ; cs = 2*log2e*c (scaled cell state, updated).
// Returns h in true units. 5 exp2 + 2 rcp.
__device__ __forceinline__ float cellP(float pi, float pf, float pg, float po, float& cs)
{
    float a = __builtin_amdgcn_exp2f(-pi);
    float u = __builtin_amdgcn_exp2f(-pf);
    float b = __builtin_amdgcn_exp2f(pg);
    float d = __builtin_amdgcn_exp2f(-po);
    float t1 = 1.0f + a;
    float t3 = 1.0f + u;
    float t2 = __builtin_fmaf(t1, b, t1);          // (1+a)(1+b)
    float bm = b - 1.0f;
    float num = __builtin_fmaf(L2E2 * bm, t3, cs * t2);
    cs = num * __builtin_amdgcn_rcpf(t2 * t3);
    float e = __builtin_amdgcn_exp2f(cs);
    float t4 = 1.0f + d;
    float t5 = __builtin_fmaf(t4, e, t4);          // (1+d)(1+e)
    return (e - 1.0f) * __builtin_amdgcn_rcpf(t5);
}

// gather this lane's gate value from the MFMA accumulator via DPP row-shifts:
// dest lane l needs element rsel=(l>>2)&3 from source lane l-4*rsel (same DPP row).
__device__ __forceinline__ float dpp_gate(int rsel, floatx4 Cg)
{
    // row_shr:4 = 0x114, row_shr:8 = 0x118, row_shr:12 = 0x11C
    float s1 = __int_as_float(__builtin_amdgcn_update_dpp(
        0, __float_as_int(Cg[1]), 0x114, 0xF, 0xF, true));
    float s2 = __int_as_float(__builtin_amdgcn_update_dpp(
        0, __float_as_int(Cg[2]), 0x118, 0xF, 0xF, true));
    float s3 = __int_as_float(__builtin_amdgcn_update_dpp(
        0, __float_as_int(Cg[3]), 0x11C, 0xF, 0xF, true));
    return rsel == 0 ? Cg[0] : (rsel == 1 ? s1 : (rsel == 2 ? s2 : s3));
}

// ---- phase segments (macros: no lambdas, no scheduling intrinsics) ----
// SEG_L0: layer-0 MFMA cluster + DPP epilogue + h1f[nxt] store. Reads xf[cur],
// h1f[cur] (written LAST phase, barrier-protected). Guarded by doA.
#define SEG_L0()                                                                     \
    if (doA) {                                                                       \
        floatx4 C0[4];                                                               \
        _Pragma("unroll") for (int g = 0; g < 4; ++g)                                \
            C0[g] = floatx4{0.f, 0.f, 0.f, 0.f};                                     \
        {                                                                            \
            half8 bx = *(const half8*)&xf[cur][lane][0];                             \
            _Pragma("unroll") for (int g = 0; g < 4; ++g)                            \
                C0[g] = MFMA(aWih0[g], bx, C0[g]);                                   \
        }                                                                            \
        _Pragma("unroll") for (int kt = 0; kt < 4; ++kt) {                           \
            half8 bh = *(const half8*)&h1f[cur][kt][lane][0];                        \
            _Pragma("unroll") for (int g = 0; g < 4; ++g)                            \
                C0[g] = MFMA(aWhh0[g][kt], bh, C0[g]);                               \
        }                                                                            \
        float g0 = dpp_gate(rsel, C0[0]);                                            \
        float g1 = dpp_gate(rsel, C0[1]);                                            \
        float g2 = dpp_gate(rsel, C0[2]);                                            \
        float g3 = dpp_gate(rsel, C0[3]);                                            \
        float h0 = cellP(g0, g1, g2, g3, cs1);                                       \
        h1f[nxt][ktD][rowD][eD] = (f16)h0;                                           \
    }

// SEG_L1: layer-1 MFMA cluster + DPP epilogue + h2f[nxt] store (+h2last at p==T_).
// Reads h1f[cur], h2f[cur], whh1lds (loop-invariant). Guarded by doB.
#define SEG_L1()                                                                     \
    if (doB) {                                                                       \
        floatx4 C1[4];                                                               \
        _Pragma("unroll") for (int g = 0; g < 4; ++g)                                \
            C1[g] = floatx4{0.f, 0.f, 0.f, 0.f};                                     \
        _Pragma("unroll") for (int kt = 0; kt < 4; ++kt) {                           \
            half8 bh = *(const half8*)&h1f[cur][kt][lane][0];                        \
            _Pragma("unroll") for (int g = 0; g < 4; ++g)                            \
                C1[g] = MFMA(aWih1[g][kt], bh, C1[g]);                               \
        }                                                                            \
        _Pragma("unroll") for (int kt = 0; kt < 2; ++kt) {                           \
            half8 bh = *(const half8*)&h2f[cur][kt][lane][0];                        \
            _Pragma("unroll") for (int g = 0; g < 4; ++g)                            \
                C1[g] = MFMA(aWhh1r[g][kt], bh, C1[g]);                              \
        }                                                                            \
        _Pragma("unroll") for (int kt = 2; kt < 4; ++kt) {                           \
            half8 bh = *(const half8*)&h2f[cur][kt][lane][0];                        \
            _Pragma("unroll") for (int g = 0; g < 4; ++g) {                          \
                half8 aw = *(const half8*)&whh1lds[wg][g][kt - 2][lane][0];          \
                C1[g] = MFMA(aw, bh, C1[g]);                                         \
            }                                                                        \
        }                                                                            \
        float g0 = dpp_gate(rsel, C1[0]) + bias1v[0];                                \
        float g1 = dpp_gate(rsel, C1[1]) + bias1v[1];                                \
        float g2 = dpp_gate(rsel, C1[2]) + bias1v[2];                                \
        float g3 = dpp_gate(rsel, C1[3]) + bias1v[3];                                \
        float hv = cellP(g0, g1, g2, g3, cs2);                                       \
        h2f[nxt][ktD][rowD][eD] = (f16)hv;                                           \
        if (p == T_)                                                                 \
            h2last[(size_t)(b0 + colp) * H_ + wg * 16 + jj2] = hv;                   \
    }

__global__ __launch_bounds__(NT, 1) void lstm_fused(
    const float* __restrict__ x,
    const float* __restrict__ Wih0, const float* __restrict__ Whh0,
    const float* __restrict__ bih0, const float* __restrict__ bhh0,
    const float* __restrict__ Wih1, const float* __restrict__ Whh1,
    const float* __restrict__ bih1, const float* __restrict__ bhh1,
    float* __restrict__ h2last)
{
    // LDS: 64 + 8 + 8 + 2 = 82 KB
    __shared__ __align__(16) f16 whh1lds[8][4][2][64][8];  // [wg][gate][kt-2][lane][e]
    __shared__ __align__(16) f16 h1f[2][4][64][8];         // [buf][kt][lane][e] B-frag
    __shared__ __align__(16) f16 h2f[2][4][64][8];
    __shared__ __align__(16) f16 xf[2][64][8];             // x_aug (K=16: 14 x, 0, 1.0)

    const int tid = threadIdx.x;
    const int lane = tid & 63;
    const int wv = tid >> 6;          // wave 0..7 == j-group for BOTH layers
    const int n = lane & 15;          // batch column (valid < NB) / A-row index
    const int q = lane >> 4;          // quad -> rows q*4+r
    const int b0 = blockIdx.x * NB;
    // anti-phase group: Y-waves {1,2,4,7} run SEG_L1 before SEG_L0.
    // 0x96 anti-phases both contiguous (0,1)(2,3)(4,5)(6,7) and round-robin
    // (0,4)(1,5)(2,6)(3,7) wave->SIMD pairings.
    const bool grpY = (0x96 >> wv) & 1;

    // ---- zero state buffers: h1f,h2f = 4096 dwords total; xf = 512 dwords ----
    {
        unsigned int* z1 = (unsigned int*)h1f;
        unsigned int* z2 = (unsigned int*)h2f;
#pragma unroll
        for (int i = 0; i < 4; ++i) {
            z1[tid + i * 512] = 0u;
            z2[tid + i * 512] = 0u;
        }
        ((unsigned int*)xf)[tid] = 0u;
    }
    __syncthreads();

    // ---- x_aug constants (k==15 -> 1.0 in BOTH buffers) + stage x(0) into xf[0] ----
    if (tid < NB) {
        xf[0][tid + 16][7] = (f16)1.0f;
        xf[1][tid + 16][7] = (f16)1.0f;
    }
    if (tid < 64) {
        int nn_ = tid & 15, kq = tid >> 4;
        if (nn_ < NB && kq < 2) {
            half8 v;
#pragma unroll
            for (int e = 0; e < 8; ++e) {
                int k = kq * 8 + e;
                v[e] = (k < D_) ? (f16)x[(size_t)(b0 + nn_) * T_ * D_ + k]
                                : (k == 15 ? (f16)1.0f : (f16)0.0f);
            }
            *(half8*)&xf[0][tid][0] = v;
        }
    }

    // incremental x-prefetch pointer (valid only for threads < NB*D_)
    const float* xpp = x + (size_t)(b0 + (tid & 3)) * T_ * D_ + D_ + (tid >> 2);

    // ---- per-wave weights: layer-0 j-group wv AND layer-1 j-group wv ----
    const int wg = wv;
    half8 aWhh0[4][4], aWih0[4];      // layer-0: all in regs
    half8 aWih1[4][4], aWhh1r[4][2];  // layer-1: Wih1 + Whh1 kt0-1 regs; kt2-3 LDS
#pragma unroll
    for (int g = 0; g < 4; ++g) {
        const float gs = (g == 2) ? L2E2 : L2E;   // g-gate rows pre-scaled 2x
        const int gr = g * 128 + wg * 16 + n;
#pragma unroll
        for (int kt = 0; kt < 4; ++kt)
            aWhh0[g][kt] = ldfrag_s(Whh0 + (size_t)gr * H_ + kt * 32 + q * 8, gs);
        half8 w0;
#pragma unroll
        for (int e = 0; e < 8; ++e) {
            int k = q * 8 + e;
            if (k < D_)       w0[e] = (f16)(Wih0[(size_t)gr * D_ + k] * gs);
            else if (k == 15) w0[e] = (f16)((bih0[gr] + bhh0[gr]) * gs);
            else              w0[e] = (f16)0.0f;
        }
        aWih0[g] = w0;
#pragma unroll
        for (int kt = 0; kt < 4; ++kt) {
            aWih1[g][kt] = ldfrag_s(Wih1 + (size_t)gr * H_ + kt * 32 + q * 8, gs);
            half8 wf = ldfrag_s(Whh1 + (size_t)gr * H_ + kt * 32 + q * 8, gs);
            if (kt < 2) aWhh1r[g][kt] = wf;
            else        *(half8*)&whh1lds[wg][g][kt - 2][lane][0] = wf;
        }
    }

    // ---- per-lane (dest-cell) constants for the DPP-redistributed epilogue ----
    const int colp = lane & 3;        // dest batch column (0..3, all valid)
    const int rsel = (lane >> 2) & 3; // source accumulator element / row-within-quad
    const int jj2 = q * 4 + rsel;     // dest cell row j within the wave's 16-row group
    const int ktD = wg >> 1;
    const int rowD = colp + 16 * ((wg & 1) * 2 + (q >> 1));
    const int eD = (q & 1) * 4 + rsel;
    float bias1v[4];
#pragma unroll
    for (int g = 0; g < 4; ++g) {
        const float gs = (g == 2) ? L2E2 : L2E;
        const int gb = g * 128 + wg * 16 + jj2;
        bias1v[g] = (bih1[gb] + bhh1[gb]) * gs;
    }

    float cs1 = 0.0f;   // layer-0 cell state for cell (jj2, colp), pre-scaled 2*log2e
    float cs2 = 0.0f;   // layer-1 cell state
    __syncthreads();

    // phase p: layer-0 computes h1(p) [p<T], layer-1 computes h2(p-1) [p>=1].
    // X-waves run L0;L1 -- Y-waves run L1;L0. Both segments read only [cur] buffers
    // and write only [nxt] slots (disjoint per wave), so segment order is free.
    for (int p = 0; p <= T_; ++p) {
        const int cur = p & 1, nxt = cur ^ 1;
        const bool doA = (p < T_);
        const bool doB = (p >= 1);

        float xp = 0.0f;
        if (tid < NB * D_ && (p + 1) < T_) xp = *xpp;

        if (!grpY) {
            SEG_L0()
            SEG_L1()
        } else {
            SEG_L1()
            SEG_L0()
        }

        if (tid < NB * D_ && (p + 1) < T_) {
            int k = tid >> 2;
            xf[nxt][(tid & 3) + 16 * (k >> 3)][k & 7] = (f16)xp;
            xpp += D_;
        }
        __syncthreads();
    }
}

// batch-norm statistics over the batch dim: 1 block, 1024 threads
__global__ void bn_stats(const float* __restrict__ h2last, float* __restrict__ stats)
{
    __shared__ float red[2][8][128];
    const int tid = threadIdx.x;
    const int j = tid & 127, bs = tid >> 7;
    float s = 0.0f, ss = 0.0f;
    for (int bb = 0; bb < 128; ++bb) {
        float v = h2last[(size_t)(bb * 8 + bs) * H_ + j];
        s += v;
        ss += v * v;
    }
    red[0][bs][j] = s;
    red[1][bs][j] = ss;
    __syncthreads();
    if (tid < 128) {
        float S = 0.0f, SS = 0.0f;
#pragma unroll
        for (int k = 0; k < 8; ++k) { S += red[0][k][tid]; SS += red[1][k][tid]; }
        float mu = S * (1.0f / 1024.0f);
        float var = SS * (1.0f / 1024.0f) - mu * mu;
        stats[tid] = mu;
        stats[128 + tid] = __builtin_amdgcn_rsqf(var + 1e-5f);
    }
}

// normalize + MLP head: 8 blocks x 128 threads, one batch element per thread
__global__ void bn_mlp(const float* __restrict__ h2last, const float* __restrict__ stats,
                       const float* __restrict__ gamma, const float* __restrict__ beta,
                       const float* __restrict__ W1, const float* __restrict__ b1,
                       const float* __restrict__ W2, const float* __restrict__ b2,
                       float* __restrict__ out)
{
    __shared__ float W1T[128][33];
    __shared__ float mus[128], isds[128], gs[128], bts[128], w2s[32];
    const int tid = threadIdx.x;
    const int b = blockIdx.x * 128 + tid;

    for (int i = tid; i < 4096; i += 128) {
        int k = i >> 7, j = i & 127;
        W1T[j][k] = W1[i];
    }
    mus[tid] = stats[tid];
    isds[tid] = stats[128 + tid];
    gs[tid] = gamma[tid];
    bts[tid] = beta[tid];
    if (tid < 32) w2s[tid] = W2[tid];
    __syncthreads();

    float z[32];
#pragma unroll
    for (int k = 0; k < 32; ++k) z[k] = b1[k];

    for (int j = 0; j < 128; ++j) {
        float nv = (h2last[(size_t)b * H_ + j] - mus[j]) * isds[j] * gs[j] + bts[j];
#pragma unroll
        for (int k = 0; k < 32; ++k) z[k] += W1T[j][k] * nv;
    }
    float o = b2[0];
#pragma unroll
    for (int k = 0; k < 32; ++k) o += w2s[k] * fmaxf(z[k], 0.0f);
    out[b] = o;
}

extern "C" void kernel_launch(void* const* d_in, const int* in_sizes, int n_in,
                              void* d_out, int out_size, void* d_ws, size_t ws_size,
                              hipStream_t stream)
{
    const float* x    = (const float*)d_in[0];
    const float* Wih0 = (const float*)d_in[1];
    const float* Whh0 = (const float*)d_in[2];
    const float* bih0 = (const float*)d_in[3];
    const float* bhh0 = (const float*)d_in[4];
    const float* Wih1 = (const float*)d_in[5];
    const float* Whh1 = (const float*)d_in[6];
    const float* bih1 = (const float*)d_in[7];
    const float* bhh1 = (const float*)d_in[8];
    const float* gamma = (const float*)d_in[9];
    const float* beta  = (const float*)d_in[10];
    const float* W1 = (const float*)d_in[11];
    const float* b1 = (const float*)d_in[12];
    const float* W2 = (const float*)d_in[13];
    const float* b2 = (const float*)d_in[14];

    float* h2last = (float*)d_ws;              // 1024*128 floats = 512 KB
    float* stats  = h2last + (size_t)B_ * H_;  // 256 floats
    float* out = (float*)d_out;

    hipLaunchKernelGGL(lstm_fused, dim3(B_ / NB), dim3(NT), 0, stream,
                       x, Wih0, Whh0, bih0, bhh0, Wih1, Whh1, bih1, bhh1, h2last);
    hipLaunchKernelGGL(bn_stats, dim3(1), dim3(1024), 0, stream, h2last, stats);
    hipLaunchKernelGGL(bn_mlp, dim3(8), dim3(128), 0, stream,
                       h2last, stats, gamma, beta, W1, b1, W2, b2, out);
}